// Round 8
// baseline (458.672 us; speedup 1.0000x reference)
//
#include <hip/hip_runtime.h>
#include <cstdint>

#define NN 100000
#define EE 1600000
#define ET (EE + NN)
#define NBUCK 782            // ceil(NN/128), 128 nodes per bucket
#define BCAP 3584            // fixed per-bucket staging capacity (mean ~2176, sd ~47)
#define LOG2E 1.4426950408889634f

typedef unsigned int u32;
typedef unsigned short u16;
typedef short bf16x8 __attribute__((ext_vector_type(8)));
typedef float f32x4 __attribute__((ext_vector_type(4)));
typedef int i32x4 __attribute__((ext_vector_type(4)));

__device__ __forceinline__ u16 f2bf(float f) {
    union { float f; u32 i; } v; v.f = f;
    u32 r = v.i + 0x7FFFu + ((v.i >> 16) & 1u);
    return (u16)(r >> 16);
}
__device__ __forceinline__ float bf2f(u32 u) {
    union { u32 i; float f; } v; v.i = u << 16; return v.f;
}
__device__ __forceinline__ void get_edge(const int* __restrict__ ei, int e, int& s, int& d) {
    if (e < EE) { s = ei[e]; d = ei[EE + e]; }
    else { s = e - EE; d = s; }
}
__device__ __forceinline__ float leaky(float x) { return x > 0.f ? x : 0.2f * x; }

// DPP row_ror rotate-reduce within 16-lane rows (VALU pipe, no LDS/bpermute).
#define DPP_ROR_F(x, CTRL) __int_as_float(__builtin_amdgcn_update_dpp(0, __float_as_int(x), (CTRL), 0xF, 0xF, true))
__device__ __forceinline__ float rmax16(float x) {
    x = fmaxf(x, DPP_ROR_F(x, 0x121));
    x = fmaxf(x, DPP_ROR_F(x, 0x122));
    x = fmaxf(x, DPP_ROR_F(x, 0x124));
    x = fmaxf(x, DPP_ROR_F(x, 0x128));
    return x;
}
__device__ __forceinline__ float rsum16(float x) {
    x += DPP_ROR_F(x, 0x121);
    x += DPP_ROR_F(x, 0x122);
    x += DPP_ROR_F(x, 0x124);
    x += DPP_ROR_F(x, 0x128);
    return x;
}

// ---------------- W prep: fp32 [k][c] -> bf16 transposed [c][k] (one-time, tiny)
__global__ __launch_bounds__(256) void wprep_kernel(
    const float* __restrict__ W1, const float* __restrict__ W2, const float* __restrict__ W3,
    u16* __restrict__ wt1, u16* __restrict__ wt2, u16* __restrict__ wt3)
{
    int i = blockIdx.x * 256 + threadIdx.x;
    if (i < 16384)      { int c = i >> 7, k = i & 127; wt1[i] = f2bf(W1[k * 128 + c]); }
    else if (i < 32768) { int j = i - 16384; int c = j >> 7, k = j & 127; wt2[j] = f2bf(W2[k * 128 + c]); }
    else if (i < 36864) { int j = i - 32768; int c = j >> 7, k = j & 127; wt3[j] = f2bf(W3[k * 32 + c]); }
}

// ---------------- MFMA GEMM + fused attn epilogue.
// Block: 64 rows x OUTC, 256 thr (4 waves). bf16 MFMA 16x16x32, fp32 accumulate.
// Verified layouts: A[m=lane&15][k=q*8+j], B[n=lane&15][k=q*8+j], C/D col=lane&15 row=q*4+reg.
// X staged bf16 (u32-packed, stride 68 u32); Wt (bf16 [c][k]) staged likewise.
// Epilogue: fp32 acc -> LDS -> exact attn dots (pre-scaled by log2e for exp2 softmax)
// + packed-bf16 h store.
template<int OUTC, bool IN16>
__global__ __launch_bounds__(256) void gemm_mfma(
    const void* __restrict__ Xv, const u16* __restrict__ Wt16g,
    const float* __restrict__ asw, const float* __restrict__ adw,
    u16* __restrict__ Hout16, float* __restrict__ as_o, float* __restrict__ ad_o)
{
    constexpr int NT = OUTC / 16;                 // N-tiles per wave: 8 or 2
    constexpr int LDSU = (OUTC == 128) ? 13056 : 6528;
    constexpr int HS = (OUTC == 128) ? 132 : 36;  // fp32 epilogue row stride
    __shared__ u32 lds[LDSU];
    u32* wl = lds + 64 * 68;

    const int tid = threadIdx.x;
    const int r0 = blockIdx.x * 64;

    // stage X -> bf16 pairs, rows stride 68 u32
    if (IN16) {
        const u32* Xg = (const u32*)Xv;
        for (int i = tid; i < 64 * 64; i += 256) {
            int r = i >> 6, k2 = i & 63;
            u32 v = 0;
            if (r0 + r < NN) v = Xg[(size_t)(r0 + r) * 64 + k2];
            lds[r * 68 + k2] = v;
        }
    } else {
        const float* Xf = (const float*)Xv;
        for (int i = tid; i < 64 * 64; i += 256) {
            int r = i >> 6, k2 = i & 63;
            u32 v = 0;
            if (r0 + r < NN) {
                float2 f = *(const float2*)(Xf + (size_t)(r0 + r) * 128 + k2 * 2);
                v = (u32)f2bf(f.x) | ((u32)f2bf(f.y) << 16);
            }
            lds[r * 68 + k2] = v;
        }
    }
    // stage Wt (bf16 [c][128]) -> rows stride 68 u32
    {
        const u32* Wg = (const u32*)Wt16g;
        for (int i = tid; i < OUTC * 64; i += 256) {
            int c = i >> 6, k2 = i & 63;
            wl[c * 68 + k2] = Wg[i];
        }
    }
    __syncthreads();

    const int w = tid >> 6, l = tid & 63;
    const int lm = l & 15, q = l >> 4;

    f32x4 acc[NT];
    #pragma unroll
    for (int T = 0; T < NT; T++)
        #pragma unroll
        for (int r = 0; r < 4; r++) acc[T][r] = 0.f;

    #pragma unroll
    for (int kc = 0; kc < 4; kc++) {
        bf16x8 af = *(const bf16x8*)&lds[(16 * w + lm) * 68 + kc * 16 + q * 4];
        #pragma unroll
        for (int T = 0; T < NT; T++) {
            bf16x8 bfr = *(const bf16x8*)&wl[(16 * T + lm) * 68 + kc * 16 + q * 4];
            acc[T] = __builtin_amdgcn_mfma_f32_16x16x32_bf16(af, bfr, acc[T], 0, 0, 0);
        }
    }
    __syncthreads();

    // dump fp32 acc tile to LDS: row = 16w + q*4 + reg, col = 16T + lm
    float* hl = (float*)lds;
    #pragma unroll
    for (int T = 0; T < NT; T++)
        #pragma unroll
        for (int rg = 0; rg < 4; rg++)
            hl[(16 * w + q * 4 + rg) * HS + 16 * T + lm] = acc[T][rg];
    __syncthreads();

    // packed bf16 h store (coalesced u32)
    for (int i = tid; i < 64 * (OUTC / 2); i += 256) {
        int r = i / (OUTC / 2), k2 = i % (OUTC / 2);
        int row = r0 + r;
        if (row < NN) {
            float a = hl[r * HS + k2 * 2];
            float b = hl[r * HS + k2 * 2 + 1];
            ((u32*)Hout16)[(size_t)row * (OUTC / 2) + k2] = (u32)f2bf(a) | ((u32)f2bf(b) << 16);
        }
    }
    // fused attn dots from fp32 h (scaled by log2e so agg kernels use exp2 directly)
    if (OUTC == 128) {
        const int row = tid >> 2, part = tid & 3;
        const float* hp = &hl[row * HS + part * 32];
        const float* aw = asw + part * 32;
        const float* dw = adw + part * 32;
        float s = 0.f, d = 0.f;
        #pragma unroll
        for (int c = 0; c < 32; c++) { float hv = hp[c]; s += hv * aw[c]; d += hv * dw[c]; }
        const int grow = r0 + row;
        if (grow < NN) {
            as_o[(size_t)grow * 4 + part] = s * LOG2E;
            ad_o[(size_t)grow * 4 + part] = d * LOG2E;
        }
    } else {
        if (tid < 64) {
            const float* hp = &hl[tid * HS];
            float s = 0.f, d = 0.f;
            #pragma unroll
            for (int c = 0; c < 32; c++) { float hv = hp[c]; s += hv * asw[c]; d += hv * adw[c]; }
            const int grow = r0 + tid;
            if (grow < NN) {
                as_o[grow] = s * LOG2E;
                ad_o[grow] = d * LOG2E;
            }
        }
    }
}

// ---------------- bucketed CSR build (unchanged)
__global__ __launch_bounds__(256) void bin_fill_kernel(const int* __restrict__ ei,
    int* __restrict__ gcur, u32* __restrict__ pairs)
{
    __shared__ int hist[NBUCK];
    __shared__ int base[NBUCK];
    const int t = threadIdx.x;
    for (int i = t; i < NBUCK; i += 256) hist[i] = 0;
    __syncthreads();
    const int chunk = (ET + gridDim.x - 1) / gridDim.x;
    const int e0 = blockIdx.x * chunk;
    const int e1 = min(e0 + chunk, ET);
    for (int e = e0 + t; e < e1; e += 256) {
        int s, d; get_edge(ei, e, s, d);
        atomicAdd(&hist[d >> 7], 1);
    }
    __syncthreads();
    for (int i = t; i < NBUCK; i += 256) {
        int c = hist[i];
        base[i] = c ? atomicAdd(&gcur[i], c) : 0;
        hist[i] = 0;
    }
    __syncthreads();
    for (int e = e0 + t; e < e1; e += 256) {
        int s, d; get_edge(ei, e, s, d);
        int b = d >> 7;
        int pos = atomicAdd(&hist[b], 1);
        pairs[(size_t)b * BCAP + base[b] + pos] = ((u32)(d & 127) << 25) | (u32)s;
    }
}

__global__ __launch_bounds__(1024) void bscan_kernel(const int* __restrict__ bcnt,
    int* __restrict__ bbase, int* __restrict__ rowp)
{
    __shared__ int lds[1024];
    const int t = threadIdx.x;
    int v = (t < NBUCK) ? bcnt[t] : 0;
    lds[t] = v;
    __syncthreads();
    for (int off = 1; off < 1024; off <<= 1) {
        int x = (t >= off) ? lds[t - off] : 0;
        __syncthreads();
        lds[t] += x;
        __syncthreads();
    }
    if (t < NBUCK) bbase[t] = lds[t] - v;
    if (t == 0) { bbase[NBUCK] = ET; rowp[NN] = ET; }
}

__global__ __launch_bounds__(256) void bucket_csr_kernel(const u32* __restrict__ pairs,
    const int* __restrict__ bcnt, const int* __restrict__ bbase,
    int* __restrict__ rowp, int* __restrict__ col)
{
    __shared__ int hist[128], scn[128];
    __shared__ int col_lds[BCAP];
    const int b = blockIdx.x;
    const int cbase = bbase[b];
    const int cnt = bcnt[b];
    const u32* pk0 = pairs + (size_t)b * BCAP;
    const int t = threadIdx.x;
    if (t < 128) hist[t] = 0;
    __syncthreads();
    for (int i = t; i < cnt; i += 256)
        atomicAdd(&hist[pk0[i] >> 25], 1);
    __syncthreads();
    if (t < 128) scn[t] = hist[t];
    __syncthreads();
    for (int off = 1; off < 128; off <<= 1) {
        int x = (t < 128 && t >= off) ? scn[t - off] : 0;
        __syncthreads();
        if (t < 128) scn[t] += x;
        __syncthreads();
    }
    if (t < 128) {
        int ex = scn[t] - hist[t];
        int node = b * 128 + t;
        if (node < NN) rowp[node] = cbase + ex;
        hist[t] = ex;
    }
    __syncthreads();
    for (int i = t; i < cnt; i += 256) {
        u32 pk = pk0[i];
        int pos = atomicAdd(&hist[pk >> 25], 1);
        if (pos < BCAP) col_lds[pos] = pk & 0x1FFFFFFu;
    }
    __syncthreads();
    for (int i = t; i < cnt; i += 256)
        col[cbase + i] = col_lds[i];
}

// ---------------- fused online-softmax aggregation, H=4.
// One node per wave; 16 edges/tile x 4 head-groups of 16 lanes.
// Gather = async DMA: 4 x global_load_lds width=16. Issue k stages rows of
// edges 4k..4k+3 (lane group l>>4 supplies edge 4k+(l>>4); per-lane source
// row + (l&15)*16; HW writes LDS at base + lane*16 -> edge i's row lands at
// byte 256*i). No register destination => hipcc cannot sink the loads: 4 KB
// guaranteed in flight. Softmax + pst round-trip + next-tile col/as prefetch
// overlap the flight; one vmcnt(0)+"memory" drain gates the LDS consumption
// (stride-1 u32 reads, 2-way bank aliasing = free).
template<bool DOELU>
__global__ __launch_bounds__(256) void agg4_kernel(
    const int* __restrict__ rowp, const int* __restrict__ col,
    const float* __restrict__ as_, const float* __restrict__ ad_,
    const u16* __restrict__ Hb16, const float* __restrict__ bias,
    u16* __restrict__ outp16)
{
    __shared__ float pst[4][64];
    __shared__ u32 rows[4][1024];     // per-wave 16 rows x 256 B
    const int tid = threadIdx.x;
    const int w = tid >> 6;
    const int lane = tid & 63;
    const int node = blockIdx.x * 4 + w;
    const int sub = lane & 15;
    const int h = lane >> 4;

    const int start = rowp[node];
    const int end   = rowp[node + 1];
    const float adv = ad_[(size_t)node * 4 + h];
    const float2 bv = *(const float2*)(bias + lane * 2);
    const int esel  = lane >> 4;          // which of 4 edges this lane serves per issue
    const int inrow = (lane & 15) << 4;   // 16 B chunk within a 256 B row
    u32* const myrows = rows[w];
    const char* const hbase = (const char*)Hb16;

    float m = -1e30f, den = 0.f, a0 = 0.f, a1 = 0.f;

    // preload tile 0
    int jj = start + sub;
    bool valid = jj < end;
    int s = valid ? col[jj] : 0;
    float lg = valid ? leaky(as_[(size_t)s * 4 + h] + adv) : -1e30f;

    for (int j0 = start; j0 < end; j0 += 16) {
        const int soff = (int)((u32)s << 8);   // byte offset of src row (256 B)

        // 4 async DMA issues; each stages 4 rows (1 KB). Cannot be sunk.
        #pragma unroll
        for (int k = 0; k < 4; k++) {
            const int ro = __shfl(soff, esel + k * 4);        // row offset of edge 4k+esel
            const char* gp = hbase + ro + inrow;
            __builtin_amdgcn_global_load_lds(
                (const __attribute__((address_space(1))) u32*)gp,
                (__attribute__((address_space(3))) u32*)(myrows + k * 256),
                16, 0, 0);
        }

        // softmax chain overlaps DMA flight
        const float cm = rmax16(lg);
        const float mnew = fmaxf(m, cm);
        const float sc = exp2f(m - mnew);
        a0 *= sc; a1 *= sc; den *= sc; m = mnew;
        const float p = valid ? exp2f(lg - m) : 0.f;
        pst[w][lane] = p;                 // same-wave DS, in-order
        den += rsum16(p);

        // software-prefetch next tile's col/as (issued before the drain)
        const int jn = j0 + 16 + sub;
        const bool nvalid = jn < end;
        const int sn = nvalid ? col[jn] : 0;
        const float asn = as_[(size_t)sn * 4 + h];

        const f32x4 pv0 = *(const f32x4*)&pst[w][h * 16 + 0];
        const f32x4 pv1 = *(const f32x4*)&pst[w][h * 16 + 4];
        const f32x4 pv2 = *(const f32x4*)&pst[w][h * 16 + 8];
        const f32x4 pv3 = *(const f32x4*)&pst[w][h * 16 + 12];

        // drain the DMA; "memory" keeps the row ds_reads below this point
        asm volatile("s_waitcnt vmcnt(0)" ::: "memory");

        #pragma unroll
        for (int i = 0; i < 16; i++) {
            const u32 wvv = myrows[i * 64 + lane];
            const float pi = (i < 4 ? pv0 : i < 8 ? pv1 : i < 12 ? pv2 : pv3)[i & 3];
            a0 += pi * bf2f(wvv & 0xffffu);
            a1 += pi * bf2f(wvv >> 16);
        }
        s = sn; valid = nvalid;
        lg = nvalid ? leaky(asn + adv) : -1e30f;
    }
    const float rden = 1.f / (den + 1e-16f);
    float v0 = a0 * rden + bv.x;
    float v1 = a1 * rden + bv.y;
    if (DOELU) {
        v0 = v0 > 0.f ? v0 : (__expf(v0) - 1.f);
        v1 = v1 > 0.f ? v1 : (__expf(v1) - 1.f);
    }
    u32 pack = (u32)f2bf(v0) | ((u32)f2bf(v1) << 16);
    *(u32*)(outp16 + (size_t)node * 128 + lane * 2) = pack;
}

// ---------------- H=1 aggregation: two nodes per wave, 32 edges/tile.
// so/p staged in LDS (b128/int4 readback), DPP 16-wide butterflies + one
// shfl_xor(16) cross-row step. Next-tile col/as prefetched. (round-2 form)
__global__ __launch_bounds__(256) void agg1_kernel(
    const int* __restrict__ rowp, const int* __restrict__ col,
    const float* __restrict__ as_, const float* __restrict__ ad_,
    const u16* __restrict__ Hb16, const float* __restrict__ bias,
    float* __restrict__ outp)
{
    __shared__ float pst[4][64];
    __shared__ int   sst[4][64];
    const int t = threadIdx.x;
    const int w = t >> 6;
    const int lane = t & 63;
    const int l32 = lane & 31;
    const int half = lane >> 5;
    const int node = blockIdx.x * 8 + (t >> 5);

    const int start = rowp[node];
    const int end   = rowp[node + 1];
    const float adv = ad_[node];
    const char* hb = (const char*)Hb16;
    const int l2 = l32 << 1;
    const float bvv = bias[l32];

    float m = -1e30f, den = 0.f, acc = 0.f;

    // preload tile 0
    int jj = start + l32;
    bool valid = jj < end;
    int s = valid ? col[jj] : 0;
    float lg = valid ? leaky(as_[s] + adv) : -1e30f;

    for (int j0 = start; j0 < end; j0 += 32) {
        float cm = rmax16(lg);
        cm = fmaxf(cm, __shfl_xor(cm, 16, 32));
        const float mnew = fmaxf(m, cm);
        const float sc = exp2f(m - mnew);
        acc *= sc; den *= sc; m = mnew;
        const float p = valid ? exp2f(lg - m) : 0.f;
        pst[w][lane] = p;
        sst[w][lane] = s << 6;            // byte offset of src row (32 bf16 = 64 B)
        float ps = rsum16(p);
        ps += __shfl_xor(ps, 16, 32);
        den += ps;

        // software-prefetch next tile's col/as
        const int jn = j0 + 32 + l32;
        const bool nvalid = jn < end;
        const int sn = nvalid ? col[jn] : 0;
        const float asn = as_[sn];

        const float* pb = &pst[w][half << 5];
        const int*   sb = &sst[w][half << 5];
        #pragma unroll
        for (int cch = 0; cch < 2; cch++) {
            const f32x4 pv0 = *(const f32x4*)(pb + cch * 16 + 0);
            const f32x4 pv1 = *(const f32x4*)(pb + cch * 16 + 4);
            const f32x4 pv2 = *(const f32x4*)(pb + cch * 16 + 8);
            const f32x4 pv3 = *(const f32x4*)(pb + cch * 16 + 12);
            const i32x4 sv0 = *(const i32x4*)(sb + cch * 16 + 0);
            const i32x4 sv1 = *(const i32x4*)(sb + cch * 16 + 4);
            const i32x4 sv2 = *(const i32x4*)(sb + cch * 16 + 8);
            const i32x4 sv3 = *(const i32x4*)(sb + cch * 16 + 12);
            #pragma unroll
            for (int i = 0; i < 16; i++) {
                const int so = (i < 4 ? sv0 : i < 8 ? sv1 : i < 12 ? sv2 : sv3)[i & 3];
                const float pi = (i < 4 ? pv0 : i < 8 ? pv1 : i < 12 ? pv2 : pv3)[i & 3];
                acc += pi * bf2f((u32)*(const u16*)(hb + so + l2));
            }
        }
        s = sn; valid = nvalid;
        lg = nvalid ? leaky(asn + adv) : -1e30f;
    }
    outp[(size_t)node * 32 + l32] = acc / (den + 1e-16f) + bvv;
}

extern "C" void kernel_launch(void* const* d_in, const int* in_sizes, int n_in,
                              void* d_out, int out_size, void* d_ws, size_t ws_size,
                              hipStream_t stream)
{
    const float* x   = (const float*)d_in[0];
    const int*   ei  = (const int*)d_in[1];
    const float* W1  = (const float*)d_in[2];
    const float* as1 = (const float*)d_in[3];
    const float* ad1 = (const float*)d_in[4];
    const float* b1  = (const float*)d_in[5];
    const float* W2  = (const float*)d_in[6];
    const float* as2 = (const float*)d_in[7];
    const float* ad2 = (const float*)d_in[8];
    const float* b2  = (const float*)d_in[9];
    const float* W3  = (const float*)d_in[10];
    const float* as3 = (const float*)d_in[11];
    const float* ad3 = (const float*)d_in[12];
    const float* b3  = (const float*)d_in[13];
    float* outp = (float*)d_out;

    char* ws = (char*)d_ws;
    u16*   hb16  = (u16*)(ws);                    // N*128 bf16 = 25.6 MB (gather source)
    u16*   xb16  = (u16*)(ws + 25700000);         // N*128 bf16 = 25.6 MB (layer input)
    u16*   h3b16 = (u16*)(ws + 51400000);         // N*32 bf16 = 6.4 MB
    float* asb   = (float*)(ws + 57900000);       // N*4 f32
    float* adb   = (float*)(ws + 59500000);       // N*4 f32
    int*   rowp  = (int*)(ws + 61100000);         // N+1 ints
    int*   col   = (int*)(ws + 61600000);         // ET ints = 6.8 MB
    u32*   pairs = (u32*)(ws + 68400032);         // NBUCK*BCAP u32 = 11.2 MB
    int*   gcur  = (int*)(ws + 79700000);         // NBUCK ints (counts after fill)
    int*   bbase = (int*)(ws + 79704096);         // NBUCK+1 ints
    u16*   wt1   = (u16*)(ws + 79710000);         // 128x128 bf16 = 32 KB
    u16*   wt2   = (u16*)(ws + 79750000);         // 32 KB
    u16*   wt3   = (u16*)(ws + 79790000);         // 32x128 bf16 = 8 KB -> ~79.8 MB total

    const dim3 B(256);
    const int gG = (NN + 63) / 64;   // 1563

    // ---------------- one-time: W transpose+bf16, bucketed CSR build
    wprep_kernel<<<144, B, 0, stream>>>(W1, W2, W3, wt1, wt2, wt3);
    hipMemsetAsync(gcur, 0, NBUCK * 4, stream);
    bin_fill_kernel<<<256, B, 0, stream>>>(ei, gcur, pairs);
    bscan_kernel<<<1, dim3(1024), 0, stream>>>(gcur, bbase, rowp);
    bucket_csr_kernel<<<NBUCK, B, 0, stream>>>(pairs, gcur, bbase, rowp, col);

    // ---------------- layer 1 (H=4)
    gemm_mfma<128, false><<<gG, B, 0, stream>>>(x, wt1, as1, ad1, hb16, asb, adb);
    agg4_kernel<true><<<NN / 4, B, 0, stream>>>(rowp, col, asb, adb, hb16, b1, xb16);

    // ---------------- layer 2 (H=4)
    gemm_mfma<128, true><<<gG, B, 0, stream>>>(xb16, wt2, as2, ad2, hb16, asb, adb);
    agg4_kernel<true><<<NN / 4, B, 0, stream>>>(rowp, col, asb, adb, hb16, b2, xb16);

    // ---------------- layer 3 (H=1, C=32)
    gemm_mfma<32, true><<<gG, B, 0, stream>>>(xb16, wt3, as3, ad3, h3b16, asb, adb);
    agg1_kernel<<<NN / 8, B, 0, stream>>>(rowp, col, asb, adb, h3b16, b3, outp);
}

// Round 9
// 433.805 us; speedup vs baseline: 1.0573x; 1.0573x over previous
//
#include <hip/hip_runtime.h>
#include <cstdint>

#define NN 100000
#define EE 1600000
#define ET (EE + NN)
#define NBUCK 782            // ceil(NN/128), 128 nodes per bucket
#define BCAP 3584            // fixed per-bucket staging capacity (mean ~2176, sd ~47)
#define LOG2E 1.4426950408889634f

typedef unsigned int u32;
typedef unsigned short u16;
typedef short bf16x8 __attribute__((ext_vector_type(8)));
typedef float f32x4 __attribute__((ext_vector_type(4)));
typedef int i32x4 __attribute__((ext_vector_type(4)));

__device__ __forceinline__ u16 f2bf(float f) {
    union { float f; u32 i; } v; v.f = f;
    u32 r = v.i + 0x7FFFu + ((v.i >> 16) & 1u);
    return (u16)(r >> 16);
}
__device__ __forceinline__ float bf2f(u32 u) {
    union { u32 i; float f; } v; v.i = u << 16; return v.f;
}
__device__ __forceinline__ void get_edge(const int* __restrict__ ei, int e, int& s, int& d) {
    if (e < EE) { s = ei[e]; d = ei[EE + e]; }
    else { s = e - EE; d = s; }
}
__device__ __forceinline__ float leaky(float x) { return x > 0.f ? x : 0.2f * x; }

// DPP row_ror rotate-reduce within 16-lane rows (VALU pipe, no LDS/bpermute).
#define DPP_ROR_F(x, CTRL) __int_as_float(__builtin_amdgcn_update_dpp(0, __float_as_int(x), (CTRL), 0xF, 0xF, true))
__device__ __forceinline__ float rmax16(float x) {
    x = fmaxf(x, DPP_ROR_F(x, 0x121));
    x = fmaxf(x, DPP_ROR_F(x, 0x122));
    x = fmaxf(x, DPP_ROR_F(x, 0x124));
    x = fmaxf(x, DPP_ROR_F(x, 0x128));
    return x;
}
__device__ __forceinline__ float rsum16(float x) {
    x += DPP_ROR_F(x, 0x121);
    x += DPP_ROR_F(x, 0x122);
    x += DPP_ROR_F(x, 0x124);
    x += DPP_ROR_F(x, 0x128);
    return x;
}

// ---------------- W prep: fp32 [k][c] -> bf16 transposed [c][k] (one-time, tiny)
__global__ __launch_bounds__(256) void wprep_kernel(
    const float* __restrict__ W1, const float* __restrict__ W2, const float* __restrict__ W3,
    u16* __restrict__ wt1, u16* __restrict__ wt2, u16* __restrict__ wt3)
{
    int i = blockIdx.x * 256 + threadIdx.x;
    if (i < 16384)      { int c = i >> 7, k = i & 127; wt1[i] = f2bf(W1[k * 128 + c]); }
    else if (i < 32768) { int j = i - 16384; int c = j >> 7, k = j & 127; wt2[j] = f2bf(W2[k * 128 + c]); }
    else if (i < 36864) { int j = i - 32768; int c = j >> 7, k = j & 127; wt3[j] = f2bf(W3[k * 32 + c]); }
}

// ---------------- MFMA GEMM + fused attn epilogue.
// Block: 64 rows x OUTC, 256 thr (4 waves). bf16 MFMA 16x16x32, fp32 accumulate.
// Verified layouts: A[m=lane&15][k=q*8+j], B[n=lane&15][k=q*8+j], C/D col=lane&15 row=q*4+reg.
// X staged bf16 (u32-packed, stride 68 u32); Wt (bf16 [c][k]) staged likewise.
// Epilogue: fp32 acc -> LDS -> exact attn dots (pre-scaled by log2e for exp2 softmax)
// + packed-bf16 h store.
template<int OUTC, bool IN16>
__global__ __launch_bounds__(256) void gemm_mfma(
    const void* __restrict__ Xv, const u16* __restrict__ Wt16g,
    const float* __restrict__ asw, const float* __restrict__ adw,
    u16* __restrict__ Hout16, float* __restrict__ as_o, float* __restrict__ ad_o)
{
    constexpr int NT = OUTC / 16;                 // N-tiles per wave: 8 or 2
    constexpr int LDSU = (OUTC == 128) ? 13056 : 6528;
    constexpr int HS = (OUTC == 128) ? 132 : 36;  // fp32 epilogue row stride
    __shared__ u32 lds[LDSU];
    u32* wl = lds + 64 * 68;

    const int tid = threadIdx.x;
    const int r0 = blockIdx.x * 64;

    // stage X -> bf16 pairs, rows stride 68 u32
    if (IN16) {
        const u32* Xg = (const u32*)Xv;
        for (int i = tid; i < 64 * 64; i += 256) {
            int r = i >> 6, k2 = i & 63;
            u32 v = 0;
            if (r0 + r < NN) v = Xg[(size_t)(r0 + r) * 64 + k2];
            lds[r * 68 + k2] = v;
        }
    } else {
        const float* Xf = (const float*)Xv;
        for (int i = tid; i < 64 * 64; i += 256) {
            int r = i >> 6, k2 = i & 63;
            u32 v = 0;
            if (r0 + r < NN) {
                float2 f = *(const float2*)(Xf + (size_t)(r0 + r) * 128 + k2 * 2);
                v = (u32)f2bf(f.x) | ((u32)f2bf(f.y) << 16);
            }
            lds[r * 68 + k2] = v;
        }
    }
    // stage Wt (bf16 [c][128]) -> rows stride 68 u32
    {
        const u32* Wg = (const u32*)Wt16g;
        for (int i = tid; i < OUTC * 64; i += 256) {
            int c = i >> 6, k2 = i & 63;
            wl[c * 68 + k2] = Wg[i];
        }
    }
    __syncthreads();

    const int w = tid >> 6, l = tid & 63;
    const int lm = l & 15, q = l >> 4;

    f32x4 acc[NT];
    #pragma unroll
    for (int T = 0; T < NT; T++)
        #pragma unroll
        for (int r = 0; r < 4; r++) acc[T][r] = 0.f;

    #pragma unroll
    for (int kc = 0; kc < 4; kc++) {
        bf16x8 af = *(const bf16x8*)&lds[(16 * w + lm) * 68 + kc * 16 + q * 4];
        #pragma unroll
        for (int T = 0; T < NT; T++) {
            bf16x8 bfr = *(const bf16x8*)&wl[(16 * T + lm) * 68 + kc * 16 + q * 4];
            acc[T] = __builtin_amdgcn_mfma_f32_16x16x32_bf16(af, bfr, acc[T], 0, 0, 0);
        }
    }
    __syncthreads();

    // dump fp32 acc tile to LDS: row = 16w + q*4 + reg, col = 16T + lm
    float* hl = (float*)lds;
    #pragma unroll
    for (int T = 0; T < NT; T++)
        #pragma unroll
        for (int rg = 0; rg < 4; rg++)
            hl[(16 * w + q * 4 + rg) * HS + 16 * T + lm] = acc[T][rg];
    __syncthreads();

    // packed bf16 h store (coalesced u32)
    for (int i = tid; i < 64 * (OUTC / 2); i += 256) {
        int r = i / (OUTC / 2), k2 = i % (OUTC / 2);
        int row = r0 + r;
        if (row < NN) {
            float a = hl[r * HS + k2 * 2];
            float b = hl[r * HS + k2 * 2 + 1];
            ((u32*)Hout16)[(size_t)row * (OUTC / 2) + k2] = (u32)f2bf(a) | ((u32)f2bf(b) << 16);
        }
    }
    // fused attn dots from fp32 h (scaled by log2e so agg kernels use exp2 directly)
    if (OUTC == 128) {
        const int row = tid >> 2, part = tid & 3;
        const float* hp = &hl[row * HS + part * 32];
        const float* aw = asw + part * 32;
        const float* dw = adw + part * 32;
        float s = 0.f, d = 0.f;
        #pragma unroll
        for (int c = 0; c < 32; c++) { float hv = hp[c]; s += hv * aw[c]; d += hv * dw[c]; }
        const int grow = r0 + row;
        if (grow < NN) {
            as_o[(size_t)grow * 4 + part] = s * LOG2E;
            ad_o[(size_t)grow * 4 + part] = d * LOG2E;
        }
    } else {
        if (tid < 64) {
            const float* hp = &hl[tid * HS];
            float s = 0.f, d = 0.f;
            #pragma unroll
            for (int c = 0; c < 32; c++) { float hv = hp[c]; s += hv * asw[c]; d += hv * adw[c]; }
            const int grow = r0 + tid;
            if (grow < NN) {
                as_o[grow] = s * LOG2E;
                ad_o[grow] = d * LOG2E;
            }
        }
    }
}

// ---------------- bucketed CSR build (unchanged)
__global__ __launch_bounds__(256) void bin_fill_kernel(const int* __restrict__ ei,
    int* __restrict__ gcur, u32* __restrict__ pairs)
{
    __shared__ int hist[NBUCK];
    __shared__ int base[NBUCK];
    const int t = threadIdx.x;
    for (int i = t; i < NBUCK; i += 256) hist[i] = 0;
    __syncthreads();
    const int chunk = (ET + gridDim.x - 1) / gridDim.x;
    const int e0 = blockIdx.x * chunk;
    const int e1 = min(e0 + chunk, ET);
    for (int e = e0 + t; e < e1; e += 256) {
        int s, d; get_edge(ei, e, s, d);
        atomicAdd(&hist[d >> 7], 1);
    }
    __syncthreads();
    for (int i = t; i < NBUCK; i += 256) {
        int c = hist[i];
        base[i] = c ? atomicAdd(&gcur[i], c) : 0;
        hist[i] = 0;
    }
    __syncthreads();
    for (int e = e0 + t; e < e1; e += 256) {
        int s, d; get_edge(ei, e, s, d);
        int b = d >> 7;
        int pos = atomicAdd(&hist[b], 1);
        pairs[(size_t)b * BCAP + base[b] + pos] = ((u32)(d & 127) << 25) | (u32)s;
    }
}

__global__ __launch_bounds__(1024) void bscan_kernel(const int* __restrict__ bcnt,
    int* __restrict__ bbase, int* __restrict__ rowp)
{
    __shared__ int lds[1024];
    const int t = threadIdx.x;
    int v = (t < NBUCK) ? bcnt[t] : 0;
    lds[t] = v;
    __syncthreads();
    for (int off = 1; off < 1024; off <<= 1) {
        int x = (t >= off) ? lds[t - off] : 0;
        __syncthreads();
        lds[t] += x;
        __syncthreads();
    }
    if (t < NBUCK) bbase[t] = lds[t] - v;
    if (t == 0) { bbase[NBUCK] = ET; rowp[NN] = ET; }
}

__global__ __launch_bounds__(256) void bucket_csr_kernel(const u32* __restrict__ pairs,
    const int* __restrict__ bcnt, const int* __restrict__ bbase,
    int* __restrict__ rowp, int* __restrict__ col)
{
    __shared__ int hist[128], scn[128];
    __shared__ int col_lds[BCAP];
    const int b = blockIdx.x;
    const int cbase = bbase[b];
    const int cnt = bcnt[b];
    const u32* pk0 = pairs + (size_t)b * BCAP;
    const int t = threadIdx.x;
    if (t < 128) hist[t] = 0;
    __syncthreads();
    for (int i = t; i < cnt; i += 256)
        atomicAdd(&hist[pk0[i] >> 25], 1);
    __syncthreads();
    if (t < 128) scn[t] = hist[t];
    __syncthreads();
    for (int off = 1; off < 128; off <<= 1) {
        int x = (t < 128 && t >= off) ? scn[t - off] : 0;
        __syncthreads();
        if (t < 128) scn[t] += x;
        __syncthreads();
    }
    if (t < 128) {
        int ex = scn[t] - hist[t];
        int node = b * 128 + t;
        if (node < NN) rowp[node] = cbase + ex;
        hist[t] = ex;
    }
    __syncthreads();
    for (int i = t; i < cnt; i += 256) {
        u32 pk = pk0[i];
        int pos = atomicAdd(&hist[pk >> 25], 1);
        if (pos < BCAP) col_lds[pos] = pk & 0x1FFFFFFu;
    }
    __syncthreads();
    for (int i = t; i < cnt; i += 256)
        col[cbase + i] = col_lds[i];
}

// ---------------- fused online-softmax aggregation, H=4.  (best verified form)
// One node per wave; 16 edges/tile x 4 head-groups of 16 lanes.
// src offsets via v_readlane (wave-uniform -> SGPR saddr addressing), p via
// 1 ds_write + 4 ds_read_b128 (same-wave DS is in-order, compiler inserts the
// lgkm wait), max/sum via DPP row_ror, exp2 throughout (logits pre-scaled by
// log2e in the GEMM epilogue). Next tile's col/as software-prefetched.
// NOTE (r3-r8): do NOT add batching/sched_barrier/DMA-staging here — all four
// mechanisms were tried; compiler re-sinks register loads (VGPR stays 32), and
// guaranteed-MLP LDS staging REGRESSED 77->88 us (occupancy + drain cost).
// TLP at ~72% occupancy already hides the gather latency.
template<bool DOELU>
__global__ __launch_bounds__(256) void agg4_kernel(
    const int* __restrict__ rowp, const int* __restrict__ col,
    const float* __restrict__ as_, const float* __restrict__ ad_,
    const u16* __restrict__ Hb16, const float* __restrict__ bias,
    u16* __restrict__ outp16)
{
    __shared__ float pst[4][64];
    const int tid = threadIdx.x;
    const int w = tid >> 6;
    const int lane = tid & 63;
    const int node = blockIdx.x * 4 + w;
    const int sub = lane & 15;
    const int h = lane >> 4;

    const int start = rowp[node];
    const int end   = rowp[node + 1];
    const float adv = ad_[(size_t)node * 4 + h];
    const int lane4 = lane << 2;
    const float2 bv = *(const float2*)(bias + lane * 2);

    float m = -1e30f, den = 0.f, a0 = 0.f, a1 = 0.f;

    // preload tile 0
    int jj = start + sub;
    bool valid = jj < end;
    int s = valid ? col[jj] : 0;
    float lg = valid ? leaky(as_[(size_t)s * 4 + h] + adv) : -1e30f;

    for (int j0 = start; j0 < end; j0 += 16) {
        const u32 soff = (u32)s << 8;     // byte offset of src row (128 bf16 = 256 B)

        // softmax chain
        const float cm = rmax16(lg);
        const float mnew = fmaxf(m, cm);
        const float sc = exp2f(m - mnew);
        a0 *= sc; a1 *= sc; den *= sc; m = mnew;
        const float p = valid ? exp2f(lg - m) : 0.f;
        pst[w][lane] = p;                 // same-wave DS, in-order: no fence needed
        den += rsum16(p);

        // software-prefetch next tile's col/as (latency hides under gathers)
        const int jn = j0 + 16 + sub;
        const bool nvalid = jn < end;
        const int sn = nvalid ? col[jn] : 0;
        const float asn = as_[(size_t)sn * 4 + h];

        const f32x4 pv0 = *(const f32x4*)&pst[w][h * 16 + 0];
        const f32x4 pv1 = *(const f32x4*)&pst[w][h * 16 + 4];
        const f32x4 pv2 = *(const f32x4*)&pst[w][h * 16 + 8];
        const f32x4 pv3 = *(const f32x4*)&pst[w][h * 16 + 12];
        #pragma unroll
        for (int i = 0; i < 16; i++) {
            const int so = __builtin_amdgcn_readlane((int)soff, i);   // SGPR
            const char* rp = (const char*)Hb16 + so;                  // uniform row ptr
            const u32 wv = *(const u32*)(rp + lane4);                 // saddr + v_lane4
            const float pi = (i < 4 ? pv0 : i < 8 ? pv1 : i < 12 ? pv2 : pv3)[i & 3];
            a0 += pi * bf2f(wv & 0xffffu);
            a1 += pi * bf2f(wv >> 16);
        }
        s = sn; valid = nvalid;
        lg = nvalid ? leaky(asn + adv) : -1e30f;
    }
    const float rden = 1.f / (den + 1e-16f);
    float v0 = a0 * rden + bv.x;
    float v1 = a1 * rden + bv.y;
    if (DOELU) {
        v0 = v0 > 0.f ? v0 : (__expf(v0) - 1.f);
        v1 = v1 > 0.f ? v1 : (__expf(v1) - 1.f);
    }
    u32 pack = (u32)f2bf(v0) | ((u32)f2bf(v1) << 16);
    *(u32*)(outp16 + (size_t)node * 128 + lane * 2) = pack;
}

// ---------------- H=1 aggregation: two nodes per wave, 32 edges/tile.
// so/p staged in LDS (b128/int4 readback), DPP 16-wide butterflies + one
// shfl_xor(16) cross-row step. Next-tile col/as prefetched.
__global__ __launch_bounds__(256) void agg1_kernel(
    const int* __restrict__ rowp, const int* __restrict__ col,
    const float* __restrict__ as_, const float* __restrict__ ad_,
    const u16* __restrict__ Hb16, const float* __restrict__ bias,
    float* __restrict__ outp)
{
    __shared__ float pst[4][64];
    __shared__ int   sst[4][64];
    const int t = threadIdx.x;
    const int w = t >> 6;
    const int lane = t & 63;
    const int l32 = lane & 31;
    const int half = lane >> 5;
    const int node = blockIdx.x * 8 + (t >> 5);

    const int start = rowp[node];
    const int end   = rowp[node + 1];
    const float adv = ad_[node];
    const char* hb = (const char*)Hb16;
    const int l2 = l32 << 1;
    const float bvv = bias[l32];

    float m = -1e30f, den = 0.f, acc = 0.f;

    // preload tile 0
    int jj = start + l32;
    bool valid = jj < end;
    int s = valid ? col[jj] : 0;
    float lg = valid ? leaky(as_[s] + adv) : -1e30f;

    for (int j0 = start; j0 < end; j0 += 32) {
        float cm = rmax16(lg);
        cm = fmaxf(cm, __shfl_xor(cm, 16, 32));
        const float mnew = fmaxf(m, cm);
        const float sc = exp2f(m - mnew);
        acc *= sc; den *= sc; m = mnew;
        const float p = valid ? exp2f(lg - m) : 0.f;
        pst[w][lane] = p;
        sst[w][lane] = s << 6;            // byte offset of src row (32 bf16 = 64 B)
        float ps = rsum16(p);
        ps += __shfl_xor(ps, 16, 32);
        den += ps;

        // software-prefetch next tile's col/as
        const int jn = j0 + 32 + l32;
        const bool nvalid = jn < end;
        const int sn = nvalid ? col[jn] : 0;
        const float asn = as_[sn];

        const float* pb = &pst[w][half << 5];
        const int*   sb = &sst[w][half << 5];
        #pragma unroll
        for (int cch = 0; cch < 2; cch++) {
            const f32x4 pv0 = *(const f32x4*)(pb + cch * 16 + 0);
            const f32x4 pv1 = *(const f32x4*)(pb + cch * 16 + 4);
            const f32x4 pv2 = *(const f32x4*)(pb + cch * 16 + 8);
            const f32x4 pv3 = *(const f32x4*)(pb + cch * 16 + 12);
            const i32x4 sv0 = *(const i32x4*)(sb + cch * 16 + 0);
            const i32x4 sv1 = *(const i32x4*)(sb + cch * 16 + 4);
            const i32x4 sv2 = *(const i32x4*)(sb + cch * 16 + 8);
            const i32x4 sv3 = *(const i32x4*)(sb + cch * 16 + 12);
            #pragma unroll
            for (int i = 0; i < 16; i++) {
                const int so = (i < 4 ? sv0 : i < 8 ? sv1 : i < 12 ? sv2 : sv3)[i & 3];
                const float pi = (i < 4 ? pv0 : i < 8 ? pv1 : i < 12 ? pv2 : pv3)[i & 3];
                acc += pi * bf2f((u32)*(const u16*)(hb + so + l2));
            }
        }
        s = sn; valid = nvalid;
        lg = nvalid ? leaky(asn + adv) : -1e30f;
    }
    outp[(size_t)node * 32 + l32] = acc / (den + 1e-16f) + bvv;
}

extern "C" void kernel_launch(void* const* d_in, const int* in_sizes, int n_in,
                              void* d_out, int out_size, void* d_ws, size_t ws_size,
                              hipStream_t stream)
{
    const float* x   = (const float*)d_in[0];
    const int*   ei  = (const int*)d_in[1];
    const float* W1  = (const float*)d_in[2];
    const float* as1 = (const float*)d_in[3];
    const float* ad1 = (const float*)d_in[4];
    const float* b1  = (const float*)d_in[5];
    const float* W2  = (const float*)d_in[6];
    const float* as2 = (const float*)d_in[7];
    const float* ad2 = (const float*)d_in[8];
    const float* b2  = (const float*)d_in[9];
    const float* W3  = (const float*)d_in[10];
    const float* as3 = (const float*)d_in[11];
    const float* ad3 = (const float*)d_in[12];
    const float* b3  = (const float*)d_in[13];
    float* outp = (float*)d_out;

    char* ws = (char*)d_ws;
    u16*   hb16  = (u16*)(ws);                    // N*128 bf16 = 25.6 MB (gather source)
    u16*   xb16  = (u16*)(ws + 25700000);         // N*128 bf16 = 25.6 MB (layer input)
    u16*   h3b16 = (u16*)(ws + 51400000);         // N*32 bf16 = 6.4 MB
    float* asb   = (float*)(ws + 57900000);       // N*4 f32
    float* adb   = (float*)(ws + 59500000);       // N*4 f32
    int*   rowp  = (int*)(ws + 61100000);         // N+1 ints
    int*   col   = (int*)(ws + 61600000);         // ET ints = 6.8 MB
    u32*   pairs = (u32*)(ws + 68400032);         // NBUCK*BCAP u32 = 11.2 MB
    int*   gcur  = (int*)(ws + 79700000);         // NBUCK ints (counts after fill)
    int*   bbase = (int*)(ws + 79704096);         // NBUCK+1 ints
    u16*   wt1   = (u16*)(ws + 79710000);         // 128x128 bf16 = 32 KB
    u16*   wt2   = (u16*)(ws + 79750000);         // 32 KB
    u16*   wt3   = (u16*)(ws + 79790000);         // 32x128 bf16 = 8 KB -> ~79.8 MB total

    const dim3 B(256);
    const int gG = (NN + 63) / 64;   // 1563

    // ---------------- one-time: W transpose+bf16, bucketed CSR build
    wprep_kernel<<<144, B, 0, stream>>>(W1, W2, W3, wt1, wt2, wt3);
    hipMemsetAsync(gcur, 0, NBUCK * 4, stream);
    bin_fill_kernel<<<256, B, 0, stream>>>(ei, gcur, pairs);
    bscan_kernel<<<1, dim3(1024), 0, stream>>>(gcur, bbase, rowp);
    bucket_csr_kernel<<<NBUCK, B, 0, stream>>>(pairs, gcur, bbase, rowp, col);

    // ---------------- layer 1 (H=4)
    gemm_mfma<128, false><<<gG, B, 0, stream>>>(x, wt1, as1, ad1, hb16, asb, adb);
    agg4_kernel<true><<<NN / 4, B, 0, stream>>>(rowp, col, asb, adb, hb16, b1, xb16);

    // ---------------- layer 2 (H=4)
    gemm_mfma<128, true><<<gG, B, 0, stream>>>(xb16, wt2, as2, ad2, hb16, asb, adb);
    agg4_kernel<true><<<NN / 4, B, 0, stream>>>(rowp, col, asb, adb, hb16, b2, xb16);

    // ---------------- layer 3 (H=1, C=32)
    gemm_mfma<32, true><<<gG, B, 0, stream>>>(xb16, wt3, as3, ad3, h3b16, asb, adb);
    agg1_kernel<<<NN / 8, B, 0, stream>>>(rowp, col, asb, adb, h3b16, b3, outp);
}